// Round 1
// baseline (33422.205 us; speedup 1.0000x reference)
//
#include <hip/hip_runtime.h>
#include <math.h>

// GPT-2 small forward: L=12 N=12 D=768 F=3072 V=50257 B=4 T=1024 HD=64
namespace {
constexpr int LAYERS = 12;
constexpr int NHEAD  = 12;
constexpr int DMODEL = 768;
constexpr int DFF    = 3072;
constexpr int VOCAB  = 50257;
constexpr int BATCH  = 4;
constexpr int SEQ    = 1024;
constexpr int HDIM   = 64;
constexpr int ROWS   = BATCH * SEQ;   // 4096

// ---------------- embedding: x = wte[tok] + wpe[t] ----------------
__global__ void k_embed(const int* __restrict__ tok, const float* __restrict__ wte,
                        const float* __restrict__ wpe, float* __restrict__ x) {
    int row = blockIdx.x;            // 0..ROWS-1
    int t   = row & (SEQ - 1);
    int tk  = tok[row];
    const float* a = wte + (size_t)tk * DMODEL;
    const float* p = wpe + (size_t)t * DMODEL;
    float* o = x + (size_t)row * DMODEL;
    for (int d = threadIdx.x; d < DMODEL; d += blockDim.x)
        o[d] = a[d] + p[d];
}

// ---------------- layernorm: one block (256 thr) per row, D=768=3*256 ----------------
__global__ void k_ln(const float* __restrict__ in, float* __restrict__ out,
                     const float* __restrict__ g, const float* __restrict__ bb) {
    int row = blockIdx.x;
    const float* xr = in + (size_t)row * DMODEL;
    float* yr = out + (size_t)row * DMODEL;
    int i0 = threadIdx.x;
    float v0 = xr[i0], v1 = xr[i0 + 256], v2 = xr[i0 + 512];
    float s  = v0 + v1 + v2;
    float ss = v0 * v0 + v1 * v1 + v2 * v2;
#pragma unroll
    for (int o = 32; o > 0; o >>= 1) {
        s  += __shfl_down(s, o, 64);
        ss += __shfl_down(ss, o, 64);
    }
    __shared__ float sh[8];
    int lane = threadIdx.x & 63, w = threadIdx.x >> 6;
    if (lane == 0) { sh[w] = s; sh[w + 4] = ss; }
    __syncthreads();
    s  = sh[0] + sh[1] + sh[2] + sh[3];
    ss = sh[4] + sh[5] + sh[6] + sh[7];
    float mean = s * (1.0f / DMODEL);
    float var  = ss * (1.0f / DMODEL) - mean * mean;
    float rstd = rsqrtf(var + 1e-5f);
    yr[i0]       = (v0 - mean) * rstd * g[i0]       + bb[i0];
    yr[i0 + 256] = (v1 - mean) * rstd * g[i0 + 256] + bb[i0 + 256];
    yr[i0 + 512] = (v2 - mean) * rstd * g[i0 + 512] + bb[i0 + 512];
}

// ---------------- tiled fp32 GEMM: C = [res +] act(A@B + bias) ----------------
// A[M,K] row-major. TRB=false: B[K,N] row-major; TRB=true: B[N,K] row-major (C=A@B^T).
// 64x64 tile, BK=16, 256 threads, 4x4 per thread.
template <bool TRB, bool GELU_ACT, bool HASRES>
__global__ void k_gemm(const float* __restrict__ A, const float* __restrict__ Bm,
                       const float* __restrict__ bias, const float* __restrict__ res,
                       float* __restrict__ C, int M, int Nn, int K) {
    __shared__ __align__(16) float As[16][68];
    __shared__ __align__(16) float Bs[16][68];
    const int tid = threadIdx.x;
    const int m0 = blockIdx.y * 64, n0 = blockIdx.x * 64;
    const int tx = tid & 15, ty = tid >> 4;
    const int am = tid >> 2, ak = (tid & 3) << 2;       // A loader: row am, 4 k's
    const int bn_nn = tid & 63, bk0 = tid >> 6;         // B loader (NN)
    const int bn_nt = tid >> 2, bk_nt = (tid & 3) << 2; // B loader (NT)
    float acc[4][4] = {};
    for (int k0 = 0; k0 < K; k0 += 16) {
        __syncthreads();
        {
            const float4 av = *(const float4*)(A + (size_t)(m0 + am) * K + k0 + ak);
            As[ak + 0][am] = av.x; As[ak + 1][am] = av.y;
            As[ak + 2][am] = av.z; As[ak + 3][am] = av.w;
        }
        if (TRB) {
            float4 bv = make_float4(0.f, 0.f, 0.f, 0.f);
            if (n0 + bn_nt < Nn)
                bv = *(const float4*)(Bm + (size_t)(n0 + bn_nt) * K + k0 + bk_nt);
            Bs[bk_nt + 0][bn_nt] = bv.x; Bs[bk_nt + 1][bn_nt] = bv.y;
            Bs[bk_nt + 2][bn_nt] = bv.z; Bs[bk_nt + 3][bn_nt] = bv.w;
        } else {
            const bool ok = (n0 + bn_nn) < Nn;
#pragma unroll
            for (int kk = bk0; kk < 16; kk += 4)
                Bs[kk][bn_nn] = ok ? Bm[(size_t)(k0 + kk) * Nn + n0 + bn_nn] : 0.f;
        }
        __syncthreads();
#pragma unroll
        for (int k = 0; k < 16; k++) {
            const float4 a4 = *(const float4*)&As[k][ty << 2];
            const float4 b4 = *(const float4*)&Bs[k][tx << 2];
            const float ar[4] = {a4.x, a4.y, a4.z, a4.w};
            const float br[4] = {b4.x, b4.y, b4.z, b4.w};
#pragma unroll
            for (int i = 0; i < 4; i++)
#pragma unroll
                for (int j = 0; j < 4; j++)
                    acc[i][j] = fmaf(ar[i], br[j], acc[i][j]);
        }
    }
#pragma unroll
    for (int i = 0; i < 4; i++) {
        const int m = m0 + (ty << 2) + i;
#pragma unroll
        for (int j = 0; j < 4; j++) {
            const int n = n0 + (tx << 2) + j;
            if (n < Nn) {
                float v = acc[i][j];
                if (bias) v += bias[n];
                if (GELU_ACT) v = 0.5f * v * (1.0f + erff(v * 0.7071067811865475f));
                if (HASRES) v += res[(size_t)m * Nn + n];
                C[(size_t)m * Nn + n] = v;
            }
        }
    }
}

// ---------------- block reductions ----------------
__device__ __forceinline__ float blk_max(float v) {
    __shared__ float sh[4];
#pragma unroll
    for (int o = 32; o > 0; o >>= 1) v = fmaxf(v, __shfl_down(v, o, 64));
    int lane = threadIdx.x & 63, w = threadIdx.x >> 6;
    __syncthreads();
    if (lane == 0) sh[w] = v;
    __syncthreads();
    return fmaxf(fmaxf(sh[0], sh[1]), fmaxf(sh[2], sh[3]));
}
__device__ __forceinline__ float blk_sum(float v) {
    __shared__ float sh[4];
#pragma unroll
    for (int o = 32; o > 0; o >>= 1) v += __shfl_down(v, o, 64);
    int lane = threadIdx.x & 63, w = threadIdx.x >> 6;
    __syncthreads();
    if (lane == 0) sh[w] = v;
    __syncthreads();
    return sh[0] + sh[1] + sh[2] + sh[3];
}

// ---------------- attention: one block per (query t, head, batch) ----------------
// qkv layout: [B*T, 3*D]; q at +h*64, k at +D+h*64, v at +2D+h*64
__global__ void k_attn(const float* __restrict__ qkv, float* __restrict__ o) {
    const int t = blockIdx.x, h = blockIdx.y, b = blockIdx.z;
    __shared__ __align__(16) float q[HDIM];
    __shared__ float sc[SEQ];
    const float* qp = qkv + ((size_t)(b * SEQ + t)) * (3 * DMODEL) + h * HDIM;
    if (threadIdx.x < HDIM) q[threadIdx.x] = qp[threadIdx.x];
    __syncthreads();
    // phase 1: scores for s<=t
    float lmax = -1e30f;
    for (int s = threadIdx.x; s <= t; s += 256) {
        const float* kp = qkv + ((size_t)(b * SEQ + s)) * (3 * DMODEL) + DMODEL + h * HDIM;
        float acc = 0.f;
#pragma unroll
        for (int d = 0; d < HDIM; d += 4) {
            const float4 kv = *(const float4*)(kp + d);
            acc += q[d] * kv.x + q[d + 1] * kv.y + q[d + 2] * kv.z + q[d + 3] * kv.w;
        }
        acc *= 0.125f;   // 1/sqrt(64)
        sc[s] = acc;
        lmax = fmaxf(lmax, acc);
    }
    const float m = blk_max(lmax);
    // phase 2: exp + sum
    float lsum = 0.f;
    for (int s = threadIdx.x; s <= t; s += 256) {
        const float e = __expf(sc[s] - m);
        sc[s] = e;
        lsum += e;
    }
    const float denom = blk_sum(lsum);   // barrier inside makes sc[] visible to all
    const float inv = 1.0f / denom;
    // phase 3: o[d] = inv * sum_s p[s]*v[s][d]; 64 d-lanes x 4 s-groups
    const int d = threadIdx.x & 63, grp = threadIdx.x >> 6;
    float acc = 0.f;
    for (int s = grp; s <= t; s += 4) {
        const float* vp = qkv + ((size_t)(b * SEQ + s)) * (3 * DMODEL) + 2 * DMODEL + h * HDIM;
        acc += sc[s] * vp[d];
    }
    __shared__ float ored[4][HDIM];
    ored[grp][d] = acc;
    __syncthreads();
    if (threadIdx.x < HDIM) {
        const float r = (ored[0][d] + ored[1][d] + ored[2][d] + ored[3][d]) * inv;
        o[((size_t)(b * SEQ + t)) * DMODEL + h * HDIM + d] = r;
    }
}
} // namespace

extern "C" void kernel_launch(void* const* d_in, const int* in_sizes, int n_in,
                              void* d_out, int out_size, void* d_ws, size_t ws_size,
                              hipStream_t stream) {
    const int*   tok  = (const int*)d_in[0];
    const float* wte  = (const float*)d_in[1];
    const float* wpe  = (const float*)d_in[2];
    const float* ln1g = (const float*)d_in[3];
    const float* ln1b = (const float*)d_in[4];
    const float* aw   = (const float*)d_in[5];
    const float* ab   = (const float*)d_in[6];
    const float* pw   = (const float*)d_in[7];
    const float* pb   = (const float*)d_in[8];
    const float* ln2g = (const float*)d_in[9];
    const float* ln2b = (const float*)d_in[10];
    const float* fw   = (const float*)d_in[11];
    const float* fb   = (const float*)d_in[12];
    const float* mw   = (const float*)d_in[13];
    const float* mb   = (const float*)d_in[14];
    const float* lnfg = (const float*)d_in[15];
    const float* lnfb = (const float*)d_in[16];
    float* out = (float*)d_out;

    // workspace layout (fp32): x | h | qkv | attn_out | mlp_hidden  = ~126 MB
    float* ws  = (float*)d_ws;
    float* x   = ws;
    float* h   = x   + (size_t)ROWS * DMODEL;
    float* qkv = h   + (size_t)ROWS * DMODEL;
    float* ao  = qkv + (size_t)ROWS * 3 * DMODEL;
    float* mh  = ao  + (size_t)ROWS * DMODEL;

    const dim3 blk(256);
    k_embed<<<ROWS, blk, 0, stream>>>(tok, wte, wpe, x);
    for (int l = 0; l < LAYERS; l++) {
        k_ln<<<ROWS, blk, 0, stream>>>(x, h, ln1g + l * DMODEL, ln1b + l * DMODEL);
        k_gemm<false, false, false><<<dim3(3 * DMODEL / 64, ROWS / 64), blk, 0, stream>>>(
            h, aw + (size_t)l * DMODEL * 3 * DMODEL, ab + l * 3 * DMODEL, nullptr,
            qkv, ROWS, 3 * DMODEL, DMODEL);
        k_attn<<<dim3(SEQ, NHEAD, BATCH), blk, 0, stream>>>(qkv, ao);
        k_gemm<false, false, true><<<dim3(DMODEL / 64, ROWS / 64), blk, 0, stream>>>(
            ao, pw + (size_t)l * DMODEL * DMODEL, pb + l * DMODEL, x,
            x, ROWS, DMODEL, DMODEL);
        k_ln<<<ROWS, blk, 0, stream>>>(x, h, ln2g + l * DMODEL, ln2b + l * DMODEL);
        k_gemm<false, true, false><<<dim3(DFF / 64, ROWS / 64), blk, 0, stream>>>(
            h, fw + (size_t)l * DMODEL * DFF, fb + l * DFF, nullptr,
            mh, ROWS, DFF, DMODEL);
        k_gemm<false, false, true><<<dim3(DMODEL / 64, ROWS / 64), blk, 0, stream>>>(
            mh, mw + (size_t)l * DFF * DMODEL, mb + l * DMODEL, x,
            x, ROWS, DMODEL, DFF);
    }
    k_ln<<<ROWS, blk, 0, stream>>>(x, h, lnfg, lnfb);
    // logits = h @ wte^T  -> d_out [4096, 50257]
    k_gemm<true, false, false><<<dim3((VOCAB + 63) / 64, ROWS / 64), blk, 0, stream>>>(
        h, wte, nullptr, nullptr, out, ROWS, VOCAB, DMODEL);
}